// Round 1
// 1780.542 us; speedup vs baseline: 1.1179x; 1.1179x over previous
//
#include <hip/hip_runtime.h>
#include <hip/hip_bf16.h>
#include <stdint.h>
#include <stddef.h>

typedef __attribute__((ext_vector_type(8))) short  short8;
typedef __attribute__((ext_vector_type(4))) short  short4v;
typedef __attribute__((ext_vector_type(4))) float  floatx4;
typedef __attribute__((ext_vector_type(4))) int    int4v;

static constexpr int MDIM = 8192;    // B*S = 4*2048
static constexpr int NDIM = 16384;   // OUT
static constexpr int KDIM = 4096;    // IN

__device__ __forceinline__ unsigned short f32_to_bf16_rne(float f) {
    union { float f; unsigned u; } v; v.f = f;
    unsigned r = v.u + 0x7fffu + ((v.u >> 16) & 1u);
    return (unsigned short)(r >> 16);
}

// ---------------- conversion kernels (fast path) ----------------

__global__ __launch_bounds__(256) void cvt_x_bf16(const float* __restrict__ x,
                                                  unsigned short* __restrict__ o) {
    size_t i = ((size_t)blockIdx.x * 256 + threadIdx.x) * 8;
    floatx4 a = *(const floatx4*)(x + i);
    floatx4 b = *(const floatx4*)(x + i + 4);
    short8 r;
    r[0] = (short)f32_to_bf16_rne(a[0]);
    r[1] = (short)f32_to_bf16_rne(a[1]);
    r[2] = (short)f32_to_bf16_rne(a[2]);
    r[3] = (short)f32_to_bf16_rne(a[3]);
    r[4] = (short)f32_to_bf16_rne(b[0]);
    r[5] = (short)f32_to_bf16_rne(b[1]);
    r[6] = (short)f32_to_bf16_rne(b[2]);
    r[7] = (short)f32_to_bf16_rne(b[3]);
    *(short8*)(o + i) = r;
}

__global__ __launch_bounds__(256) void cvt_w_bf16(const int* __restrict__ w,
                                                  unsigned short* __restrict__ o) {
    size_t i = ((size_t)blockIdx.x * 256 + threadIdx.x) * 8;
    int4v a = *(const int4v*)(w + i);
    int4v b = *(const int4v*)(w + i + 4);
    short8 r;
    // codes in [-64,63] are exact in bf16
    r[0] = (short)f32_to_bf16_rne((float)a[0]);
    r[1] = (short)f32_to_bf16_rne((float)a[1]);
    r[2] = (short)f32_to_bf16_rne((float)a[2]);
    r[3] = (short)f32_to_bf16_rne((float)a[3]);
    r[4] = (short)f32_to_bf16_rne((float)b[0]);
    r[5] = (short)f32_to_bf16_rne((float)b[1]);
    r[6] = (short)f32_to_bf16_rne((float)b[2]);
    r[7] = (short)f32_to_bf16_rne((float)b[3]);
    *(short8*)(o + i) = r;
}

// ---------------- async global->LDS helper ----------------

__device__ __forceinline__ void global_to_lds16(const unsigned short* g, unsigned short* l) {
    __builtin_amdgcn_global_load_lds(
        (__attribute__((address_space(1))) void*)(uintptr_t)g,
        (__attribute__((address_space(3))) void*)l,
        16, 0, 0);
}

// ---------------- main GEMM: 256x256 tile, BK=32, 4-buf LDS pipeline ----------------
// C[m,n] = (sum_k A[m,k]*B[n,k]) * scale[n] + bias[n]
// A: [M,K] bf16 row-major, B: [N,K] bf16 row-major (B^T input)
//
// Pipeline: body(t) stages tile t+3 (4x global_load_lds), ds_reads tile t,
// 32 MFMA, then s_waitcnt vmcnt(8) (tiles t+2,t+3 stay in flight) + s_barrier.
// Safety: buf staged in body(t) was last read in body(t-1); those ds_reads are
// drained (MFMA operand deps) before body(t-1)'s barrier, and the stage is
// issued after it.  vmcnt(8) guarantees tile t+1's 4 loads have landed.

static constexpr int BM2 = 256, BN2 = 256, BK2 = 32;

#define PIPE_STAGE(SBUF)                                              \
    do {                                                              \
        global_to_lds16(pA0, &smem[SBUF][0][wid16][0]);               \
        global_to_lds16(pA1, &smem[SBUF][0][128 + wid16][0]);         \
        global_to_lds16(pB0, &smem[SBUF][1][wid16][0]);               \
        global_to_lds16(pB1, &smem[SBUF][1][128 + wid16][0]);         \
        pA0 += BK2; pA1 += BK2; pB0 += BK2; pB1 += BK2;               \
    } while (0)

#define PIPE_BODY(CBUF, SBUF, DO_STAGE, VM)                           \
    do {                                                              \
        if (DO_STAGE) { PIPE_STAGE(SBUF); }                           \
        short8 af[8], bfr[4];                                         \
        _Pragma("unroll")                                             \
        for (int mt = 0; mt < 8; ++mt)                                \
            af[mt] = *(const short8*)&smem[CBUF][0][arow + mt * 16][kcol]; \
        _Pragma("unroll")                                             \
        for (int nt = 0; nt < 4; ++nt)                                \
            bfr[nt] = *(const short8*)&smem[CBUF][1][brow + nt * 16][kcol]; \
        _Pragma("unroll")                                             \
        for (int mt = 0; mt < 8; ++mt)                                \
            _Pragma("unroll")                                         \
            for (int nt = 0; nt < 4; ++nt)                            \
                acc[mt][nt] = __builtin_amdgcn_mfma_f32_16x16x32_bf16(\
                    af[mt], bfr[nt], acc[mt][nt], 0, 0, 0);           \
        asm volatile("s_waitcnt vmcnt(" #VM ")" ::: "memory");        \
        __builtin_amdgcn_s_barrier();                                 \
        asm volatile("" ::: "memory");                                \
    } while (0)

__global__ __launch_bounds__(512, 2) void gemm_bf16_pipe(
        const unsigned short* __restrict__ A,
        const unsigned short* __restrict__ Bm,
        const float* __restrict__ scale,
        const float* __restrict__ bias,
        float* __restrict__ C) {
    // [buf][0=A,1=B][row][col] : 4 * 2 * 256 * 32 * 2B = 128 KiB
    __shared__ __align__(16) unsigned short smem[4][2][256][32];

    const int tid   = threadIdx.x;
    const int wid   = tid >> 6;
    const int ln    = tid & 63;
    const int wid16 = wid << 4;

    // XCD-aware bijective swizzle: 2048 blocks, 2048 % 8 == 0
    const int lin = (int)blockIdx.x;
    const int swz = (lin & 7) * 256 + (lin >> 3);
    const int bm  = swz >> 6;   // 0..31
    const int bn  = swz & 63;   // 0..63

    // wave grid 2(M) x 4(N): each wave owns 128x64 of the 256x256 tile
    const int wm = wid >> 2;
    const int wn = wid & 3;

    // ---- staging source (pre-swizzled column; LDS dest stays linear) ----
    // thread t covers LDS bytes t*16: row sr = t>>2 (64 B/row), col (t&3)*8 elems.
    // read-side swizzle col ^= ((row>>1)&3)<<3 -> source col gets same XOR.
    const int sr  = tid >> 2;                                  // 0..127
    const int scc = ((tid & 3) * 8) ^ (((sr >> 1) & 3) << 3);
    const unsigned short* pA0 = A  + (size_t)(bm * BM2 + sr) * KDIM + scc;
    const unsigned short* pA1 = pA0 + (size_t)128 * KDIM;
    const unsigned short* pB0 = Bm + (size_t)(bn * BN2 + sr) * KDIM + scc;
    const unsigned short* pB1 = pB0 + (size_t)128 * KDIM;

    // ---- fragment read coords (swizzled; row bits 1-2 == (ln&15) bits 1-2) ----
    const int arow = wm * 128 + (ln & 15);
    const int brow = wn * 64  + (ln & 15);
    const int kcol = ((ln >> 4) * 8) ^ ((((ln & 15) >> 1) & 3) << 3);

    floatx4 acc[8][4];
    const floatx4 zero4 = {0.0f, 0.0f, 0.0f, 0.0f};
    #pragma unroll
    for (int i = 0; i < 8; ++i)
        #pragma unroll
        for (int j = 0; j < 4; ++j) acc[i][j] = zero4;

    // ---- prologue: stage tiles 0,1,2; wait for tile 0 (8 = tiles 1,2 in flight) ----
    PIPE_STAGE(0);
    PIPE_STAGE(1);
    PIPE_STAGE(2);
    asm volatile("s_waitcnt vmcnt(8)" ::: "memory");
    __builtin_amdgcn_s_barrier();
    asm volatile("" ::: "memory");

    // ---- main loop: tiles 0..123 (stage t+3 -> buf (t+3)&3, vmcnt(8)) ----
    for (int it = 0; it < 31; ++it) {
        PIPE_BODY(0, 3, true, 8);
        PIPE_BODY(1, 0, true, 8);
        PIPE_BODY(2, 1, true, 8);
        PIPE_BODY(3, 2, true, 8);
    }
    // ---- tail: tiles 124..127 ----
    PIPE_BODY(0, 3, true, 8);    // stages tile 127 -> buf3; tiles 126,127 in flight
    PIPE_BODY(1, 0, false, 4);   // tile 126 landed; 127 in flight
    PIPE_BODY(2, 0, false, 0);   // tile 127 landed
    PIPE_BODY(3, 0, false, 0);

    // ---- epilogue: C/D layout col=lane&15, row=(lane>>4)*4+reg (m89/m91) ----
    const int row0 = bm * BM2 + wm * 128 + (ln >> 4) * 4;
    const int col0 = bn * BN2 + wn * 64 + (ln & 15);
    #pragma unroll
    for (int nt = 0; nt < 4; ++nt) {
        const int col = col0 + nt * 16;
        const float sc = scale[col];
        const float bs = bias[col];
        #pragma unroll
        for (int mt = 0; mt < 8; ++mt) {
            float* cp = C + (size_t)(row0 + mt * 16) * NDIM + col;
            #pragma unroll
            for (int r = 0; r < 4; ++r)
                cp[(size_t)r * NDIM] = fmaf(acc[mt][nt][r], sc, bs);
        }
    }
}

// ---------------- fallback: fused convert+GEMM (used only if ws too small) ----------------

static constexpr int BM = 128, BN = 128, BK = 32;

__global__ __launch_bounds__(256) void gemm_fused(
        const float* __restrict__ A,
        const int* __restrict__ W,
        const float* __restrict__ scale,
        const float* __restrict__ bias,
        float* __restrict__ C) {
    __shared__ __align__(16) unsigned short sA[BM * BK];
    __shared__ __align__(16) unsigned short sB[BN * BK];

    const int tid = threadIdx.x;
    const int wv = tid >> 6, ln = tid & 63;
    const int bmi = blockIdx.y, bni = blockIdx.x;
    const int wm = wv >> 1, wn = wv & 1;
    const int aoff = (wm * 64 + (ln & 15)) * BK + (ln >> 4) * 8;
    const int boff = (wn * 64 + (ln & 15)) * BK + (ln >> 4) * 8;

    floatx4 acc[4][4];
    const floatx4 zero4 = {0.0f, 0.0f, 0.0f, 0.0f};
    #pragma unroll
    for (int i = 0; i < 4; ++i)
        #pragma unroll
        for (int j = 0; j < 4; ++j) acc[i][j] = zero4;

    for (int kt = 0; kt < KDIM; kt += BK) {
        __syncthreads();
        #pragma unroll
        for (int j = 0; j < 4; ++j) {
            int u = tid + j * 256;
            int row = u >> 3;
            int c4 = (u & 7) * 4;
            floatx4 av = *(const floatx4*)(A + (size_t)(bmi * BM + row) * KDIM + kt + c4);
            short4v as;
            as[0] = (short)f32_to_bf16_rne(av[0]);
            as[1] = (short)f32_to_bf16_rne(av[1]);
            as[2] = (short)f32_to_bf16_rne(av[2]);
            as[3] = (short)f32_to_bf16_rne(av[3]);
            *(short4v*)(sA + row * BK + c4) = as;
            int4v wq = *(const int4v*)(W + (size_t)(bni * BN + row) * KDIM + kt + c4);
            short4v bs;
            bs[0] = (short)f32_to_bf16_rne((float)wq[0]);
            bs[1] = (short)f32_to_bf16_rne((float)wq[1]);
            bs[2] = (short)f32_to_bf16_rne((float)wq[2]);
            bs[3] = (short)f32_to_bf16_rne((float)wq[3]);
            *(short4v*)(sB + row * BK + c4) = bs;
        }
        __syncthreads();

        short8 af[4], bfr[4];
        #pragma unroll
        for (int t = 0; t < 4; ++t) {
            af[t]  = *(const short8*)(sA + aoff + t * 16 * BK);
            bfr[t] = *(const short8*)(sB + boff + t * 16 * BK);
        }
        #pragma unroll
        for (int mt = 0; mt < 4; ++mt)
            #pragma unroll
            for (int nt = 0; nt < 4; ++nt)
                acc[mt][nt] = __builtin_amdgcn_mfma_f32_16x16x32_bf16(
                    af[mt], bfr[nt], acc[mt][nt], 0, 0, 0);
    }

    const int row0 = bmi * BM + wm * 64 + (ln >> 4) * 4;
    const int col0 = bni * BN + wn * 64 + (ln & 15);
    #pragma unroll
    for (int nt = 0; nt < 4; ++nt) {
        const int col = col0 + nt * 16;
        const float sc = scale[col];
        const float bs = bias[col];
        #pragma unroll
        for (int mt = 0; mt < 4; ++mt) {
            float* cp = C + (size_t)(row0 + mt * 16) * NDIM + col;
            #pragma unroll
            for (int r = 0; r < 4; ++r)
                cp[(size_t)r * NDIM] = fmaf(acc[mt][nt][r], sc, bs);
        }
    }
}

// ---------------- launch ----------------

extern "C" void kernel_launch(void* const* d_in, const int* in_sizes, int n_in,
                              void* d_out, int out_size, void* d_ws, size_t ws_size,
                              hipStream_t stream) {
    const float* x     = (const float*)d_in[0];
    const int*   w     = (const int*)d_in[1];
    const float* scale = (const float*)d_in[2];
    const float* bias  = (const float*)d_in[3];
    float* out = (float*)d_out;

    const size_t xElems = (size_t)MDIM * KDIM;
    const size_t wElems = (size_t)NDIM * KDIM;
    const size_t need   = (xElems + wElems) * sizeof(unsigned short);

    if (ws_size >= need) {
        unsigned short* xb = (unsigned short*)d_ws;
        unsigned short* wb = xb + xElems;
        cvt_x_bf16<<<(unsigned)(xElems / (256 * 8)), 256, 0, stream>>>(x, xb);
        cvt_w_bf16<<<(unsigned)(wElems / (256 * 8)), 256, 0, stream>>>(w, wb);
        dim3 grid((MDIM / BM2) * (NDIM / BN2));   // 2048 blocks
        gemm_bf16_pipe<<<grid, 512, 0, stream>>>(xb, wb, scale, bias, out);
    } else {
        dim3 grid(NDIM / BN, MDIM / BM);
        gemm_fused<<<grid, 256, 0, stream>>>(x, w, scale, bias, out);
    }
}